// Round 9
// baseline (159.622 us; speedup 1.0000x reference)
//
#include <hip/hip_runtime.h>

// VQ-VAE vector quantizer, MI355X — MFMA candidate-filter + exact fp32 recheck.
// z_e: [32,64,32,32] f32, codebook: [1024,64] f32.
// d_out = q_out(2097152) | loss(1) | perplexity(1) | encodings(33554432), all f32.
//
// Pipeline:
//   1. vq_prep_kernel   : codebook->bf16, squared norms (exact chain), hist zero
//   2. vq_argmin_kernel : MFMA approx distances (2 passes) -> candidate flags ->
//                         exact fp32 recheck (bit-identical to the r5 kernel's
//                         d-values & tie-break) + fused enc zero-fill, one-hot,
//                         q_out, loss, hist
//   3. vq_finalize_kernel: loss mean + perplexity
//
// Correctness: selection is ALWAYS by exact fp32 d = (zsq + ensq) - 2*dot with
// sequential fmaf chains (c ascending) and lower-index tie-break — the same
// bits as rounds 1-7 (absmax 0). MFMA only prunes: a code is exact-checked iff
// approx(-2dot_bf16) <= rowmin + margin, margin >= 2*|dot_bf16-dot|max bound
// (2^-8*1.1*||z||*||e||max*2, ||e||<=8/1024 hard) + ensq range + slack.
//
// ws layout (4-byte units):
//   [0,1024)       hist (int)
//   [1024,2048)    ensq (float)
//   [2048,34816)   cb_bf16 (1024x64 ushort = 32768 dwords)
//   [34816,35328)  partials (float[512])

#define NROWS 32768
#define KC    1024
#define DD    64
#define HW    1024
#define CHW   65536

typedef float f32x2 __attribute__((ext_vector_type(2)));
typedef float f32x4 __attribute__((ext_vector_type(4)));
typedef short bf16x8 __attribute__((ext_vector_type(8)));

__device__ __forceinline__ unsigned short f2bf(float f) {
  unsigned x = __float_as_uint(f);
  return (unsigned short)((x + 0x7fffu + ((x >> 16) & 1u)) >> 16);  // RNE
}

__global__ __launch_bounds__(256) void vq_prep_kernel(
    const float* __restrict__ cb, float* __restrict__ ensq,
    unsigned short* __restrict__ cbb, int* __restrict__ hist) {
  int k = blockIdx.x * 256 + threadIdx.x;   // 4 blocks x 256 = exactly KC
  hist[k] = 0;
  const float* row = cb + k * DD;
  float s = 0.f;
#pragma unroll
  for (int c = 0; c < DD; ++c) {
    float v = row[c];
    s = fmaf(v, v, s);                      // exact chain, c ascending
    cbb[k * DD + c] = f2bf(v);
  }
  ensq[k] = s;
}

__global__ __launch_bounds__(512) void vq_argmin_kernel(
    const float* __restrict__ z_e, const float* __restrict__ cb,
    const unsigned short* __restrict__ cbb, const float* __restrict__ ensq_g,
    float* __restrict__ qout, float* __restrict__ enc,
    int* __restrict__ hist, float* __restrict__ partials) {
  __shared__ float s_m[2][64];
  __shared__ float s_zsq[64];
  __shared__ unsigned long long s_key[64];
  __shared__ float s_loss[8];

  const int tid  = threadIdx.x;
  const int lane = tid & 63;
  const int wave = __builtin_amdgcn_readfirstlane(tid >> 6);
  const int rt   = wave & 3;    // row tile: rows [16rt, 16rt+16) of the block
  const int h    = wave >> 2;   // code half: codes [512h, 512h+512)
  const int cq   = lane >> 4;   // k-slice quarter 0..3
  const int cl   = lane & 15;   // col (code) / A-row index

  // prologue: exact zsq per row (sequential chain — same bits as r1-r7) + key init
  if (wave == 0) {
    const int n0 = blockIdx.x * 64 + lane;
    const float* zp0 = z_e + (size_t)(n0 >> 10) * CHW + (n0 & (HW - 1));
    float s = 0.f;
#pragma unroll
    for (int c = 0; c < DD; ++c) {
      float v = zp0[(size_t)c << 10];
      s = fmaf(v, v, s);
    }
    s_zsq[lane] = s;
    s_key[lane] = ~0ull;
  }

  // A-frags: this wave's 16 z-rows as bf16. Lane l: row = cl, k = cq*8+i.
  const int n  = blockIdx.x * 64 + rt * 16 + cl;
  const int b  = n >> 10;
  const int hw = n & (HW - 1);
  const float* zp = z_e + (size_t)b * CHW + hw;
  bf16x8 a0, a1;
#pragma unroll
  for (int i = 0; i < 8; ++i) {
    a0[i] = (short)f2bf(zp[(size_t)(cq * 8 + i) << 10]);
    a1[i] = (short)f2bf(zp[(size_t)(32 + cq * 8 + i) << 10]);
  }

  // fused encodings zero-fill: 64 f32x2 slots/thread across the two passes
  f32x2* enc2 = (f32x2*)(enc + (size_t)blockIdx.x * 64 * KC);

  const int kbase = h * 512;
  float bestm[4];
#pragma unroll
  for (int r = 0; r < 4; ++r) bestm[r] = 3.402823466e38f;

  // ---- pass 1: approx row-min over this wave's 512 codes ----
  for (int t = 0; t < 32; ++t) {
    { f32x2 zz = {0.f, 0.f};
      __builtin_nontemporal_store(zz, &enc2[t * 512 + tid]); }
    const int code = kbase + t * 16 + cl;
    bf16x8 b0 = *(const bf16x8*)(cbb + code * DD + cq * 8);
    bf16x8 b1 = *(const bf16x8*)(cbb + code * DD + 32 + cq * 8);
    f32x4 acc = {0.f, 0.f, 0.f, 0.f};
    acc = __builtin_amdgcn_mfma_f32_16x16x32_bf16(a0, b0, acc, 0, 0, 0);
    acc = __builtin_amdgcn_mfma_f32_16x16x32_bf16(a1, b1, acc, 0, 0, 0);
#pragma unroll
    for (int r = 0; r < 4; ++r) bestm[r] = fminf(bestm[r], -2.0f * acc[r]);
  }
  // reduce over the 16 cols (lane bits 0..3)
#pragma unroll
  for (int r = 0; r < 4; ++r) {
#pragma unroll
    for (int off = 1; off < 16; off <<= 1)
      bestm[r] = fminf(bestm[r], __shfl_xor(bestm[r], off, 64));
  }
  if (cl == 0) {
#pragma unroll
    for (int r = 0; r < 4; ++r) s_m[h][rt * 16 + cq * 4 + r] = bestm[r];
  }
  __syncthreads();

  // thresholds: global approx min + rigorous margin
  float th[4];
#pragma unroll
  for (int r = 0; r < 4; ++r) {
    const int lr = rt * 16 + cq * 4 + r;
    float mh = fminf(s_m[0][lr], s_m[1][lr]);
    th[r] = mh + 2.5e-4f * sqrtf(s_zsq[lr]) + 2.0e-4f;
  }

  // ---- pass 2: recompute (deterministic), flag, exact-check candidates ----
  for (int t = 0; t < 32; ++t) {
    { f32x2 zz = {0.f, 0.f};
      __builtin_nontemporal_store(zz, &enc2[(32 + t) * 512 + tid]); }
    const int code = kbase + t * 16 + cl;
    bf16x8 b0 = *(const bf16x8*)(cbb + code * DD + cq * 8);
    bf16x8 b1 = *(const bf16x8*)(cbb + code * DD + 32 + cq * 8);
    f32x4 acc = {0.f, 0.f, 0.f, 0.f};
    acc = __builtin_amdgcn_mfma_f32_16x16x32_bf16(a0, b0, acc, 0, 0, 0);
    acc = __builtin_amdgcn_mfma_f32_16x16x32_bf16(a1, b1, acc, 0, 0, 0);
#pragma unroll
    for (int r = 0; r < 4; ++r) {
      const bool fl = (-2.0f * acc[r] <= th[r]);
      if (__any(fl)) {
        if (fl) {
          const int lr = rt * 16 + cq * 4 + r;
          const int n2 = blockIdx.x * 64 + lr;
          const float* zp2 = z_e + (size_t)(n2 >> 10) * CHW + (n2 & (HW - 1));
          const float* ce  = cb + (size_t)code * DD;
          float dot = 0.f;
#pragma unroll 8
          for (int c = 0; c < DD; ++c)
            dot = fmaf(zp2[(size_t)c << 10], ce[c], dot);   // exact chain
          float d = (s_zsq[lr] + ensq_g[code]) - 2.0f * dot; // exact d-grid
          unsigned long long key =
              ((unsigned long long)__float_as_uint(d) << 32) | (unsigned)code;
          atomicMin(&s_key[lr], key);   // min d, then min index (numpy tie-break)
        }
      }
    }
  }
  __syncthreads();   // drains zero-fill stores; s_key final

  // one-hot 1.0 scatter + histogram (row = lane)
  const int bif = (int)(unsigned)(s_key[lane] & 0xffffffffull);
  if (wave == 0) {
    atomicAdd(&hist[bif], 1);
    enc[(size_t)n /* == blk*64+lane for wave 0 (rt=0,cl covers 0..15? no) */ * 0 +
        (size_t)(blockIdx.x * 64 + lane) * KC + bif] = 1.0f;
  }

  // fused epilogue: q_out write + loss partial (8 waves x 8 channels, row=lane)
  const int n3  = blockIdx.x * 64 + lane;
  const int b3  = n3 >> 10;
  const int hw3 = n3 & (HW - 1);
  const float* zp3   = z_e + (size_t)b3 * CHW + hw3;
  const float* cbrow = cb + (size_t)bif * DD;
  float* qp = qout + (size_t)b3 * CHW + hw3;
  float lacc = 0.f;
#pragma unroll
  for (int j = 0; j < 8; ++j) {
    int c = wave * 8 + j;
    float v    = cbrow[c];
    float zc   = zp3[(size_t)c << 10];
    float diff = v - zc;               // matches ref (quantized - ze)
    qp[(size_t)c << 10] = zc + diff;   // matches ref ze + (quantized - ze)
    lacc = fmaf(diff, diff, lacc);
  }
#pragma unroll
  for (int off = 32; off > 0; off >>= 1) lacc += __shfl_down(lacc, off, 64);
  if (lane == 0) s_loss[wave] = lacc;
  __syncthreads();
  if (tid == 0) {
    float t = 0.f;
#pragma unroll
    for (int w2 = 0; w2 < 8; ++w2) t += s_loss[w2];
    partials[blockIdx.x] = t;
  }
}

__global__ __launch_bounds__(1024) void vq_finalize_kernel(
    const int* __restrict__ hist, const float* __restrict__ partials,
    float* __restrict__ out_loss, float* __restrict__ out_ppl) {
  __shared__ float red[1024];
  const int t = threadIdx.x;

  float p   = (float)hist[t] * (1.0f / 32768.0f);
  float ent = p * logf(p + 1e-10f);
  red[t] = ent;
  __syncthreads();
  for (int s = 512; s > 0; s >>= 1) {
    if (t < s) red[t] += red[t + s];
    __syncthreads();
  }
  float entropy = red[0];
  __syncthreads();

  red[t] = (t < 512) ? partials[t] : 0.f;
  __syncthreads();
  for (int s = 512; s > 0; s >>= 1) {
    if (t < s) red[t] += red[t + s];
    __syncthreads();
  }
  if (t == 0) {
    *out_loss = 0.25f * (red[0] * (1.0f / 2097152.0f));
    *out_ppl  = expf(-entropy);
  }
}

extern "C" void kernel_launch(void* const* d_in, const int* in_sizes, int n_in,
                              void* d_out, int out_size, void* d_ws, size_t ws_size,
                              hipStream_t stream) {
  const float* z_e = (const float*)d_in[0];
  const float* cb  = (const float*)d_in[1];

  float* out  = (float*)d_out;
  float* qout = out;                       // 2097152
  float* loss = out + 2097152;
  float* ppl  = out + 2097153;
  float* enc  = out + 2097154;             // 33554432 floats

  int*            hist     = (int*)d_ws;
  float*          ensq     = (float*)d_ws + 1024;
  unsigned short* cbb      = (unsigned short*)((float*)d_ws + 2048);
  float*          partials = (float*)d_ws + 34816;

  vq_prep_kernel<<<4, 256, 0, stream>>>(cb, ensq, cbb, hist);
  vq_argmin_kernel<<<512, 512, 0, stream>>>(z_e, cb, cbb, ensq, qout, enc, hist, partials);
  vq_finalize_kernel<<<1, 1024, 0, stream>>>(hist, partials, loss, ppl);
}